// Round 2
// baseline (420.046 us; speedup 1.0000x reference)
//
#include <hip/hip_runtime.h>
#include <hip/hip_bf16.h>
#include <cstdint>

typedef __hip_bfloat16 bf16;

#define HW_T 4096   // H*W = 64*64
#define B_T  4

__device__ __forceinline__ float cvt(float v) { return v; }
__device__ __forceinline__ float cvt(bf16 v)  { return __bfloat162float(v); }

__device__ __forceinline__ void store4(float* p, const float v[4]) {
    *reinterpret_cast<float4*>(p) = make_float4(v[0], v[1], v[2], v[3]);
}

// ---------------------------------------------------------------------------
// Tiled GEMM: C[b] (M x 4096) = A (M x K, f32 weights) * B[b] + bias
// BT=false: B[b] is (K x 4096) channel-major.  BT=true: B[b] is (4096 x K)
// pixel-major (transposed access, staged through LDS).
// 64x64 tile, K_TILE=32, 256 threads, 4x4 micro-tile per thread.
// ---------------------------------------------------------------------------
template <typename TB, bool BT, bool BIAS>
__global__ __launch_bounds__(256) void gemm_tile(
    const float* __restrict__ A, const TB* __restrict__ B,
    const float* __restrict__ bias, float* __restrict__ C, int M, int K)
{
    __shared__ float As[32][65];   // [k][m]
    __shared__ float Bs[32][65];   // [k][n]
    const int tid = threadIdx.x;
    const int n0  = blockIdx.x * 64;
    const int m0  = blockIdx.y * 64;
    const int b   = blockIdx.z;
    const TB* Bp  = B + (size_t)b * K * HW_T;
    float* Cp     = C + (size_t)b * M * HW_T;
    const int tx = tid & 15, ty = tid >> 4;
    float acc[4][4] = {};

    for (int k0 = 0; k0 < K; k0 += 32) {
        #pragma unroll
        for (int i = 0; i < 8; ++i) {
            int idx = i * 256 + tid;
            int m = idx >> 5, kk = idx & 31;
            As[kk][m] = A[(size_t)(m0 + m) * K + (k0 + kk)];
            if constexpr (BT) {
                int n = idx >> 5, kb = idx & 31;
                Bs[kb][n] = cvt(Bp[(size_t)(n0 + n) * K + (k0 + kb)]);
            } else {
                int kb = idx >> 6, n = idx & 63;
                Bs[kb][n] = cvt(Bp[(size_t)(k0 + kb) * HW_T + (n0 + n)]);
            }
        }
        __syncthreads();
        #pragma unroll
        for (int kk = 0; kk < 32; ++kk) {
            float a[4], bb[4];
            #pragma unroll
            for (int i = 0; i < 4; ++i) a[i] = As[kk][ty * 4 + i];
            #pragma unroll
            for (int j = 0; j < 4; ++j) bb[j] = Bs[kk][tx * 4 + j];
            #pragma unroll
            for (int i = 0; i < 4; ++i)
                #pragma unroll
                for (int j = 0; j < 4; ++j) acc[i][j] += a[i] * bb[j];
        }
        __syncthreads();
    }

    #pragma unroll
    for (int i = 0; i < 4; ++i) {
        int m = m0 + ty * 4 + i;
        float bv = BIAS ? bias[m] : 0.0f;
        float vv[4];
        #pragma unroll
        for (int j = 0; j < 4; ++j) vv[j] = acc[i][j] + bv;
        store4(Cp + (size_t)m * HW_T + n0 + tx * 4, vv);
    }
}

// ---------------------------------------------------------------------------
// attn[b, hw, n*16+q] = sum_d dot_w[n,q,d] * k[b, n*64+d, hw]
// block = 256 pixels of one (b, n); dot_w[n] staged in LDS
// ---------------------------------------------------------------------------
__global__ __launch_bounds__(256) void attn_logits(
    const float* __restrict__ kv, const float* __restrict__ dot_w,
    float* __restrict__ attn)
{
    const int tid = threadIdx.x;
    const int hw  = blockIdx.x * 256 + tid;
    const int n   = blockIdx.y;
    const int b   = blockIdx.z;
    __shared__ float dw[1024];  // [q][d]
    for (int i = tid; i < 1024; i += 256) dw[i] = dot_w[n * 1024 + i];
    __syncthreads();

    const float* kp = kv + ((size_t)b * 512 + n * 64) * HW_T + hw;
    float acc[16] = {};
    #pragma unroll 8
    for (int d = 0; d < 64; ++d) {
        float kvv = kp[(size_t)d * HW_T];
        #pragma unroll
        for (int q = 0; q < 16; ++q) acc[q] += dw[q * 64 + d] * kvv;
    }
    float4* ap = reinterpret_cast<float4*>(attn + ((size_t)b * HW_T + hw) * 64 + n * 16);
    ap[0] = make_float4(acc[0],  acc[1],  acc[2],  acc[3]);
    ap[1] = make_float4(acc[4],  acc[5],  acc[6],  acc[7]);
    ap[2] = make_float4(acc[8],  acc[9],  acc[10], acc[11]);
    ap[3] = make_float4(acc[12], acc[13], acc[14], acc[15]);
}

// ---------------------------------------------------------------------------
// hv[b, hw, n, d] = sum_dd head_w[d, n*64+dd] * v[b, n*64+dd, hw]
// (head projection folded through the attention-value sum)
// ---------------------------------------------------------------------------
__global__ __launch_bounds__(256) void hv_proj(
    const float* __restrict__ kv, const float* __restrict__ head_w,
    float* __restrict__ hv)
{
    const int tid = threadIdx.x;
    const int hw  = blockIdx.x * 256 + tid;
    const int n   = blockIdx.y;
    const int b   = blockIdx.z;
    __shared__ float wn[4096];  // [d][dd] = head_w[d*256 + n*64 + dd]
    for (int i = tid; i < 4096; i += 256)
        wn[i] = head_w[(i >> 6) * 256 + n * 64 + (i & 63)];
    __syncthreads();

    const float* vp = kv + ((size_t)b * 512 + 256 + n * 64) * HW_T + hw;
    float acc[64] = {};
    #pragma unroll 2
    for (int dd = 0; dd < 64; ++dd) {
        float vv = vp[(size_t)dd * HW_T];
        #pragma unroll
        for (int d = 0; d < 64; ++d) acc[d] += wn[d * 64 + dd] * vv;
    }
    float* op = hv + (((size_t)b * HW_T + hw) * 4 + n) * 64;
    #pragma unroll
    for (int d = 0; d < 64; d += 4) {
        float vv[4] = {acc[d], acc[d + 1], acc[d + 2], acc[d + 3]};
        store4(op + d, vv);
    }
}

// ---------------------------------------------------------------------------
// One wave per pixel.
// Phase A: lane = (n,q): gather 9 window logits (OOB logit = 0.0, matching the
//          reference's zero-padded unfold), softmax, store P to LDS.
// Phase B: lane = d: y[b,hw,q*64+d] = head_b[d] + sum_{n,l} P[n,q,l]*hv[nb_l,n,d]
// ---------------------------------------------------------------------------
__global__ __launch_bounds__(256) void attn_apply(
    const float* __restrict__ attn, const float* __restrict__ hv,
    const float* __restrict__ head_b, bf16* __restrict__ y)
{
    const int wv   = threadIdx.x >> 6;
    const int lane = threadIdx.x & 63;
    const int hw   = blockIdx.x * 4 + wv;
    const int b    = blockIdx.y;
    const int h    = hw >> 6, w = hw & 63;
    __shared__ float P[4][64][9];

    {
        float lg[9];
        #pragma unroll
        for (int i = 0; i < 3; ++i)
            #pragma unroll
            for (int j = 0; j < 3; ++j) {
                int hh = h + i - 1, ww = w + j - 1;
                bool ok = ((unsigned)hh < 64u) && ((unsigned)ww < 64u);
                lg[i * 3 + j] = ok ? attn[((size_t)b * HW_T + hh * 64 + ww) * 64 + lane]
                                   : 0.0f;
            }
        float m = lg[0];
        #pragma unroll
        for (int l = 1; l < 9; ++l) m = fmaxf(m, lg[l]);
        float e[9], s = 0.f;
        #pragma unroll
        for (int l = 0; l < 9; ++l) { e[l] = __expf(lg[l] - m); s += e[l]; }
        float inv = 1.0f / s;
        #pragma unroll
        for (int l = 0; l < 9; ++l) P[wv][lane][l] = e[l] * inv;
    }
    __syncthreads();

    float acc[16];
    float hb = head_b[lane];
    #pragma unroll
    for (int q = 0; q < 16; ++q) acc[q] = hb;

    #pragma unroll
    for (int n = 0; n < 4; ++n) {
        #pragma unroll
        for (int i = 0; i < 3; ++i)
            #pragma unroll
            for (int j = 0; j < 3; ++j) {
                int hh = h + i - 1, ww = w + j - 1;
                if (((unsigned)hh < 64u) && ((unsigned)ww < 64u)) {  // wave-uniform
                    float hval = hv[(((size_t)b * HW_T + hh * 64 + ww) * 4 + n) * 64 + lane];
                    #pragma unroll
                    for (int q = 0; q < 16; ++q)
                        acc[q] += P[wv][n * 16 + q][i * 3 + j] * hval;
                }
            }
    }
    bf16* yp = y + ((size_t)b * HW_T + hw) * 1024 + lane;
    #pragma unroll
    for (int q = 0; q < 16; ++q) yp[q * 64] = __float2bfloat16(acc[q]);
}

// ---------------------------------------------------------------------------
extern "C" void kernel_launch(void* const* d_in, const int* in_sizes, int n_in,
                              void* d_out, int out_size, void* d_ws, size_t ws_size,
                              hipStream_t stream) {
    (void)in_sizes; (void)n_in; (void)out_size; (void)ws_size;
    const float* x      = (const float*)d_in[0];   // (4,256,64,64)
    const float* kv_w   = (const float*)d_in[1];   // (512,256)
    const float* dot_w  = (const float*)d_in[2];   // (4,16,64)
    const float* head_w = (const float*)d_in[3];   // (64,256)
    const float* head_b = (const float*)d_in[4];   // (64,)
    const float* q_w    = (const float*)d_in[5];   // (256,1024)
    const float* q_b    = (const float*)d_in[6];   // (256,)
    float* z = (float*)d_out;                      // (4,256,64,64)

    // workspace: kv f32 33.55MB | attn f32 4.19MB | hv f32 16.78MB | y bf16 33.55MB
    char* ws    = (char*)d_ws;
    float* kv   = (float*)ws;                                    // (B,512,HW)
    float* attn = (float*)(ws + 33554432);                       // (B,HW,64)
    float* hv   = (float*)(ws + 33554432 + 4194304);             // (B,HW,4,64)
    bf16*  y    = (bf16*) (ws + 33554432 + 4194304 + 16777216);  // (B,HW,1024)

    // K1: kv = kv_w @ x         (M=512, K=256)
    gemm_tile<float, false, false>
        <<<dim3(64, 8, B_T), 256, 0, stream>>>(kv_w, x, nullptr, kv, 512, 256);
    // K2: attention logits
    attn_logits<<<dim3(16, 4, B_T), 256, 0, stream>>>(kv, dot_w, attn);
    // K3: hv = head_w(block n) @ v
    hv_proj<<<dim3(16, 4, B_T), 256, 0, stream>>>(kv, head_w, hv);
    // K4: windowed softmax + apply -> y (pixel-major, bf16)
    attn_apply<<<dim3(1024, B_T), 256, 0, stream>>>(attn, hv, head_b, y);
    // K5: z = q_w @ y + q_b     (M=256, K=1024, B pixel-major bf16)
    gemm_tile<bf16, true, true>
        <<<dim3(64, 4, B_T), 256, 0, stream>>>(q_w, y, q_b, z, 256, 1024);
}

// Round 3
// 222.387 us; speedup vs baseline: 1.8888x; 1.8888x over previous
//
#include <hip/hip_runtime.h>
#include <hip/hip_bf16.h>
#include <cstdint>

typedef __hip_bfloat16 bf16;
using bf16x8 = __attribute__((ext_vector_type(8))) short;  // 8 bf16 (4 VGPRs)
using f32x4  = __attribute__((ext_vector_type(4))) float;

#define HW_T 4096   // H*W = 64*64
#define B_T  4

__device__ __forceinline__ float b2f(bf16 h) { return __bfloat162float(h); }
__device__ __forceinline__ unsigned short f2b_bits(float f) {
    bf16 h = __float2bfloat16(f);
    return *reinterpret_cast<unsigned short*>(&h);
}
__device__ __forceinline__ void store4(float* p, const float v[4]) {
    *reinterpret_cast<float4*>(p) = make_float4(v[0], v[1], v[2], v[3]);
}
__device__ __forceinline__ void store4(bf16* p, const float v[4]) {
    ushort4 pk;
    pk.x = f2b_bits(v[0]); pk.y = f2b_bits(v[1]);
    pk.z = f2b_bits(v[2]); pk.w = f2b_bits(v[3]);
    *reinterpret_cast<ushort4*>(p) = pk;
}

// async global->LDS, 16B per lane; LDS dest = wave-uniform base + lane*16
__device__ __forceinline__ void async_copy16(const bf16* g, bf16* l) {
    __builtin_amdgcn_global_load_lds(
        (const __attribute__((address_space(1))) void*)g,
        (__attribute__((address_space(3))) void*)l, 16, 0, 0);
}

// ---------------------------------------------------------------------------
// fp32 -> bf16 weight convert
// ---------------------------------------------------------------------------
__global__ __launch_bounds__(256) void convert_w(
    const float* __restrict__ a, bf16* __restrict__ o, int n)
{
    int i = blockIdx.x * 256 + threadIdx.x;
    if (i < n) o[i] = __float2bfloat16(a[i]);
}

// ---------------------------------------------------------------------------
// x (b, 256, 4096) fp32 -> xT (b, 4096, 256) bf16   (32x32 LDS tile)
// ---------------------------------------------------------------------------
__global__ __launch_bounds__(256) void transpose_x(
    const float* __restrict__ x, bf16* __restrict__ xT)
{
    __shared__ float t[32][33];
    const int b  = blockIdx.z;
    const int c0 = blockIdx.y * 32;
    const int p0 = blockIdx.x * 32;
    const int tx = threadIdx.x & 31, ty = threadIdx.x >> 5;  // 32 x 8
    const float* xp = x + ((size_t)b * 256 + c0) * HW_T + p0;
    #pragma unroll
    for (int i = 0; i < 4; ++i)
        t[ty + i * 8][tx] = xp[(size_t)(ty + i * 8) * HW_T + tx];
    __syncthreads();
    bf16* op = xT + ((size_t)b * HW_T + p0) * 256 + c0;
    #pragma unroll
    for (int i = 0; i < 4; ++i)
        op[(size_t)(ty + i * 8) * 256 + tx] = __float2bfloat16(t[tx][ty + i * 8]);
}

// ---------------------------------------------------------------------------
// MFMA GEMM (m97 structure): C[b] (M x 4096) = A (M x K) * Bt[b] (4096 x K)^T
// A, Bt bf16 row-major along K; C fp32 row-major. 128x128 tile, BK=32,
// 256 threads (4 waves, 2x2), 4x4 16x16x32 MFMAs per wave per k-tile.
// LDS layout [quad][row][8] = 16B slots, contiguous in global_load_lds order.
// ---------------------------------------------------------------------------
template <bool BIAS>
__global__ __launch_bounds__(256) void gemm_mfma_bt(
    const bf16* __restrict__ A, const bf16* __restrict__ Bt,
    const float* __restrict__ bias, float* __restrict__ C, int M, int K)
{
    __shared__ __align__(16) bf16 As[4][128][8];  // [k>>3][m][k&7]  8KB
    __shared__ __align__(16) bf16 Bs[4][128][8];  // [k>>3][n][k&7]  8KB
    const int tid  = threadIdx.x;
    const int wave = tid >> 6, lane = tid & 63;
    const int n0 = blockIdx.x * 128, m0 = blockIdx.y * 128, b = blockIdx.z;
    const bf16* Bp = Bt + (size_t)b * HW_T * K;
    float* Cp      = C + (size_t)b * M * HW_T;

    const int fi = lane & 15, quad = lane >> 4;
    const int wm = (wave >> 1) * 64, wn = (wave & 1) * 64;

    f32x4 acc[4][4] = {};

    for (int k0 = 0; k0 < K; k0 += 32) {
        #pragma unroll
        for (int t = 0; t < 2; ++t) {
            const int base = wave * 128 + t * 64;          // wave-uniform slot base
            const int slot = base + lane;
            const int q = slot >> 7, rr = slot & 127;
            bf16* ldsA = &As[0][0][0] + (size_t)base * 8;
            bf16* ldsB = &Bs[0][0][0] + (size_t)base * 8;
            async_copy16(A  + (size_t)(m0 + rr) * K + k0 + q * 8, ldsA);
            async_copy16(Bp + (size_t)(n0 + rr) * K + k0 + q * 8, ldsB);
        }
        __syncthreads();
        bf16x8 af[4], bfr[4];
        #pragma unroll
        for (int i = 0; i < 4; ++i)
            af[i] = *(const bf16x8*)&As[quad][wm + i * 16 + fi][0];
        #pragma unroll
        for (int j = 0; j < 4; ++j)
            bfr[j] = *(const bf16x8*)&Bs[quad][wn + j * 16 + fi][0];
        #pragma unroll
        for (int i = 0; i < 4; ++i)
            #pragma unroll
            for (int j = 0; j < 4; ++j)
                acc[i][j] = __builtin_amdgcn_mfma_f32_16x16x32_bf16(
                    af[i], bfr[j], acc[i][j], 0, 0, 0);
        __syncthreads();
    }

    #pragma unroll
    for (int i = 0; i < 4; ++i) {
        const int row0 = m0 + wm + i * 16 + quad * 4;
        #pragma unroll
        for (int r = 0; r < 4; ++r) {
            const float bv = BIAS ? bias[row0 + r] : 0.0f;
            #pragma unroll
            for (int j = 0; j < 4; ++j) {
                const int col = n0 + wn + j * 16 + fi;
                Cp[(size_t)(row0 + r) * HW_T + col] = acc[i][j][r] + bv;
            }
        }
    }
}

// ---------------------------------------------------------------------------
// attn[b, hw, n*16+q] = sum_d dot_w[n,q,d] * k[b, n*64+d, hw]
// ---------------------------------------------------------------------------
__global__ __launch_bounds__(256) void attn_logits(
    const float* __restrict__ kv, const float* __restrict__ dot_w,
    float* __restrict__ attn)
{
    const int tid = threadIdx.x;
    const int hw  = blockIdx.x * 256 + tid;
    const int n   = blockIdx.y;
    const int b   = blockIdx.z;
    __shared__ float dw[1024];  // [q][d]
    for (int i = tid; i < 1024; i += 256) dw[i] = dot_w[n * 1024 + i];
    __syncthreads();

    const float* kp = kv + ((size_t)b * 512 + n * 64) * HW_T + hw;
    float acc[16] = {};
    #pragma unroll 8
    for (int d = 0; d < 64; ++d) {
        float kvv = kp[(size_t)d * HW_T];
        #pragma unroll
        for (int q = 0; q < 16; ++q) acc[q] += dw[q * 64 + d] * kvv;
    }
    float4* ap = reinterpret_cast<float4*>(attn + ((size_t)b * HW_T + hw) * 64 + n * 16);
    ap[0] = make_float4(acc[0],  acc[1],  acc[2],  acc[3]);
    ap[1] = make_float4(acc[4],  acc[5],  acc[6],  acc[7]);
    ap[2] = make_float4(acc[8],  acc[9],  acc[10], acc[11]);
    ap[3] = make_float4(acc[12], acc[13], acc[14], acc[15]);
}

// ---------------------------------------------------------------------------
// hv[b, hw, n, d] = sum_dd head_w[d, n*64+dd] * v[b, n*64+dd, hw]   (bf16 out)
// ---------------------------------------------------------------------------
__global__ __launch_bounds__(256) void hv_proj(
    const float* __restrict__ kv, const float* __restrict__ head_w,
    bf16* __restrict__ hv)
{
    const int tid = threadIdx.x;
    const int hw  = blockIdx.x * 256 + tid;
    const int n   = blockIdx.y;
    const int b   = blockIdx.z;
    __shared__ float wn[4096];  // [d][dd] = head_w[d*256 + n*64 + dd]
    for (int i = tid; i < 4096; i += 256)
        wn[i] = head_w[(i >> 6) * 256 + n * 64 + (i & 63)];
    __syncthreads();

    const float* vp = kv + ((size_t)b * 512 + 256 + n * 64) * HW_T + hw;
    float acc[64] = {};
    #pragma unroll 2
    for (int dd = 0; dd < 64; ++dd) {
        float vv = vp[(size_t)dd * HW_T];
        #pragma unroll
        for (int d = 0; d < 64; ++d) acc[d] += wn[d * 64 + dd] * vv;
    }
    bf16* op = hv + (((size_t)b * HW_T + hw) * 4 + n) * 64;
    #pragma unroll
    for (int d = 0; d < 64; d += 4) {
        float vv[4] = {acc[d], acc[d + 1], acc[d + 2], acc[d + 3]};
        store4(op + d, vv);
    }
}

// ---------------------------------------------------------------------------
// One wave per pixel: zero-padded 3x3 softmax + apply -> y (b, hw, 1024) bf16
// ---------------------------------------------------------------------------
__global__ __launch_bounds__(256) void attn_apply(
    const float* __restrict__ attn, const bf16* __restrict__ hv,
    const float* __restrict__ head_b, bf16* __restrict__ y)
{
    const int wv   = threadIdx.x >> 6;
    const int lane = threadIdx.x & 63;
    const int hw   = blockIdx.x * 4 + wv;
    const int b    = blockIdx.y;
    const int h    = hw >> 6, w = hw & 63;
    __shared__ float P[4][64][9];

    {
        float lg[9];
        #pragma unroll
        for (int i = 0; i < 3; ++i)
            #pragma unroll
            for (int j = 0; j < 3; ++j) {
                int hh = h + i - 1, ww = w + j - 1;
                bool ok = ((unsigned)hh < 64u) && ((unsigned)ww < 64u);
                lg[i * 3 + j] = ok ? attn[((size_t)b * HW_T + hh * 64 + ww) * 64 + lane]
                                   : 0.0f;
            }
        float m = lg[0];
        #pragma unroll
        for (int l = 1; l < 9; ++l) m = fmaxf(m, lg[l]);
        float e[9], s = 0.f;
        #pragma unroll
        for (int l = 0; l < 9; ++l) { e[l] = __expf(lg[l] - m); s += e[l]; }
        float inv = 1.0f / s;
        #pragma unroll
        for (int l = 0; l < 9; ++l) P[wv][lane][l] = e[l] * inv;
    }
    __syncthreads();

    float acc[16];
    float hb = head_b[lane];
    #pragma unroll
    for (int q = 0; q < 16; ++q) acc[q] = hb;

    #pragma unroll
    for (int n = 0; n < 4; ++n) {
        #pragma unroll
        for (int i = 0; i < 3; ++i)
            #pragma unroll
            for (int j = 0; j < 3; ++j) {
                int hh = h + i - 1, ww = w + j - 1;
                if (((unsigned)hh < 64u) && ((unsigned)ww < 64u)) {  // wave-uniform
                    float hval = b2f(hv[(((size_t)b * HW_T + hh * 64 + ww) * 4 + n) * 64 + lane]);
                    #pragma unroll
                    for (int q = 0; q < 16; ++q)
                        acc[q] += P[wv][n * 16 + q][i * 3 + j] * hval;
                }
            }
    }
    bf16* yp = y + ((size_t)b * HW_T + hw) * 1024 + lane;
    #pragma unroll
    for (int q = 0; q < 16; ++q) yp[q * 64] = __float2bfloat16(acc[q]);
}

// ---------------------------------------------------------------------------
extern "C" void kernel_launch(void* const* d_in, const int* in_sizes, int n_in,
                              void* d_out, int out_size, void* d_ws, size_t ws_size,
                              hipStream_t stream) {
    (void)in_sizes; (void)n_in; (void)out_size; (void)ws_size;
    const float* x      = (const float*)d_in[0];   // (4,256,64,64)
    const float* kv_w   = (const float*)d_in[1];   // (512,256)
    const float* dot_w  = (const float*)d_in[2];   // (4,16,64)
    const float* head_w = (const float*)d_in[3];   // (64,256)
    const float* head_b = (const float*)d_in[4];   // (64,)
    const float* q_w    = (const float*)d_in[5];   // (256,1024)
    const float* q_b    = (const float*)d_in[6];   // (256,)
    float* z = (float*)d_out;                      // (4,256,64,64)

    // workspace layout (76.7 MB):
    //   kv   f32  (B,512,HW)    33554432 B @ 0
    //   attn f32  (B,HW,64)      4194304 B @ 33554432
    //   hv   bf16 (B,HW,4,64)    8388608 B @ 37748736
    //   y    bf16 (B,HW,1024)   33554432 B @ 46137344
    //   xT   bf16 (B,HW,256)     8388608 B @ 46137344  (aliases y: xT consumed
    //                                                    by K1 before K4 writes y)
    //   kvw_b bf16 (512,256)      262144 B @ 79691776
    //   qw_b  bf16 (256,1024)     524288 B @ 79953920
    char* ws     = (char*)d_ws;
    float* kv    = (float*)ws;
    float* attn  = (float*)(ws + 33554432);
    bf16*  hv    = (bf16*) (ws + 37748736);
    bf16*  y     = (bf16*) (ws + 46137344);
    bf16*  xT    = y;
    bf16*  kvw_b = (bf16*) (ws + 79691776);
    bf16*  qw_b  = (bf16*) (ws + 79953920);

    // P0: weight converts + x transpose (fp32 -> bf16)
    convert_w<<<dim3(512),  256, 0, stream>>>(kv_w, kvw_b, 512 * 256);
    convert_w<<<dim3(1024), 256, 0, stream>>>(q_w,  qw_b,  256 * 1024);
    transpose_x<<<dim3(128, 8, B_T), 256, 0, stream>>>(x, xT);

    // K1: kv = kv_w @ x  (M=512, K=256)  MFMA
    gemm_mfma_bt<false><<<dim3(32, 4, B_T), 256, 0, stream>>>(
        kvw_b, xT, nullptr, kv, 512, 256);
    // K2: attention logits
    attn_logits<<<dim3(16, 4, B_T), 256, 0, stream>>>(kv, dot_w, attn);
    // K3: hv = head_w(block n) @ v
    hv_proj<<<dim3(16, 4, B_T), 256, 0, stream>>>(kv, head_w, hv);
    // K4: windowed softmax + apply -> y
    attn_apply<<<dim3(1024, B_T), 256, 0, stream>>>(attn, hv, head_b, y);
    // K5: z = q_w @ y + q_b  (M=256, K=1024)  MFMA
    gemm_mfma_bt<true><<<dim3(32, 2, B_T), 256, 0, stream>>>(
        qw_b, y, q_b, z, 256, 1024);
}

// Round 4
// 158.331 us; speedup vs baseline: 2.6530x; 1.4046x over previous
//
#include <hip/hip_runtime.h>
#include <hip/hip_bf16.h>
#include <cstdint>

typedef __hip_bfloat16 bf16;
using bf16x8 = __attribute__((ext_vector_type(8))) short;  // 8 bf16 (4 VGPRs)
using f32x4  = __attribute__((ext_vector_type(4))) float;

#define HW_T 4096   // H*W = 64*64
#define B_T  4

__device__ __forceinline__ float b2f(bf16 h) { return __bfloat162float(h); }

// async global->LDS, 16B per lane; LDS dest = wave-uniform base + lane*16
__device__ __forceinline__ void async_copy16(const bf16* g, bf16* l) {
    __builtin_amdgcn_global_load_lds(
        (const __attribute__((address_space(1))) void*)g,
        (__attribute__((address_space(3))) void*)l, 16, 0, 0);
}

// ---------------------------------------------------------------------------
// Fused weights: W (384 x 256) bf16.
//   rows   0..63  : W[n*16+q, c] = sum_d dot_w[n,q,d] * kv_w[n*64+d, c]
//   rows  64..319 : W[64+n*64+dh, c] = sum_dd head_w[dh, n*64+dd] * kv_w[256+n*64+dd, c]
//   rows 320..383 : 0 (pad to N-tile)
// ---------------------------------------------------------------------------
__global__ __launch_bounds__(256) void fuse_w(
    const float* __restrict__ kv_w, const float* __restrict__ dot_w,
    const float* __restrict__ head_w, bf16* __restrict__ W)
{
    const int r = blockIdx.x;    // 0..383
    const int c = threadIdx.x;   // 0..255
    float acc = 0.f;
    if (r < 64) {
        const int n = r >> 4, q = r & 15;
        #pragma unroll 8
        for (int d = 0; d < 64; ++d)
            acc += dot_w[(n * 16 + q) * 64 + d] * kv_w[(size_t)(n * 64 + d) * 256 + c];
    } else if (r < 320) {
        const int rr = r - 64, n = rr >> 6, dh = rr & 63;
        #pragma unroll 8
        for (int dd = 0; dd < 64; ++dd)
            acc += head_w[dh * 256 + n * 64 + dd] * kv_w[(size_t)(256 + n * 64 + dd) * 256 + c];
    }
    W[r * 256 + c] = __float2bfloat16(acc);
}

// ---------------------------------------------------------------------------
// fp32 -> bf16 convert
// ---------------------------------------------------------------------------
__global__ __launch_bounds__(256) void convert_w(
    const float* __restrict__ a, bf16* __restrict__ o, int n)
{
    int i = blockIdx.x * 256 + threadIdx.x;
    if (i < n) o[i] = __float2bfloat16(a[i]);
}

// ---------------------------------------------------------------------------
// x (b, 256, 4096) fp32 -> xT (b, 4096, 256) bf16   (32x32 LDS tile)
// ---------------------------------------------------------------------------
__global__ __launch_bounds__(256) void transpose_x(
    const float* __restrict__ x, bf16* __restrict__ xT)
{
    __shared__ float t[32][33];
    const int b  = blockIdx.z;
    const int c0 = blockIdx.y * 32;
    const int p0 = blockIdx.x * 32;
    const int tx = threadIdx.x & 31, ty = threadIdx.x >> 5;  // 32 x 8
    const float* xp = x + ((size_t)b * 256 + c0) * HW_T + p0;
    #pragma unroll
    for (int i = 0; i < 4; ++i)
        t[ty + i * 8][tx] = xp[(size_t)(ty + i * 8) * HW_T + tx];
    __syncthreads();
    bf16* op = xT + ((size_t)b * HW_T + p0) * 256 + c0;
    #pragma unroll
    for (int i = 0; i < 4; ++i)
        op[(size_t)(ty + i * 8) * 256 + tx] = __float2bfloat16(t[tx][ty + i * 8]);
}

// ---------------------------------------------------------------------------
// MFMA GEMM (m97 structure): C (M x N tiles) = A (M x K) * Bt (N x K)^T
// A, Bt bf16 row-major along K; C fp32 row-major with leading dim ldC.
// Per-batch strides sA, sB, sC (0 = shared operand). 128x128 tile, BK=32,
// 256 threads (4 waves, 2x2), 4x4 16x16x32 MFMAs per wave per k-tile.
// ---------------------------------------------------------------------------
template <bool BIAS>
__global__ __launch_bounds__(256) void gemm_mfma_bt(
    const bf16* __restrict__ A, const bf16* __restrict__ Bt,
    const float* __restrict__ bias, float* __restrict__ C,
    int K, int ldC, long sA, long sB, long sC)
{
    __shared__ __align__(16) bf16 As[4][128][8];  // [k>>3][m][k&7]  8KB
    __shared__ __align__(16) bf16 Bs[4][128][8];  // [k>>3][n][k&7]  8KB
    const int tid  = threadIdx.x;
    const int wave = tid >> 6, lane = tid & 63;
    const int n0 = blockIdx.x * 128, m0 = blockIdx.y * 128, b = blockIdx.z;
    const bf16* Ap = A  + (size_t)b * sA;
    const bf16* Bp = Bt + (size_t)b * sB;
    float* Cp      = C  + (size_t)b * sC;

    const int fi = lane & 15, quad = lane >> 4;
    const int wm = (wave >> 1) * 64, wn = (wave & 1) * 64;

    f32x4 acc[4][4] = {};

    for (int k0 = 0; k0 < K; k0 += 32) {
        #pragma unroll
        for (int t = 0; t < 2; ++t) {
            const int base = wave * 128 + t * 64;          // wave-uniform slot base
            const int slot = base + lane;
            const int q = slot >> 7, rr = slot & 127;
            bf16* ldsA = &As[0][0][0] + (size_t)base * 8;
            bf16* ldsB = &Bs[0][0][0] + (size_t)base * 8;
            async_copy16(Ap + (size_t)(m0 + rr) * K + k0 + q * 8, ldsA);
            async_copy16(Bp + (size_t)(n0 + rr) * K + k0 + q * 8, ldsB);
        }
        __syncthreads();
        bf16x8 af[4], bfr[4];
        #pragma unroll
        for (int i = 0; i < 4; ++i)
            af[i] = *(const bf16x8*)&As[quad][wm + i * 16 + fi][0];
        #pragma unroll
        for (int j = 0; j < 4; ++j)
            bfr[j] = *(const bf16x8*)&Bs[quad][wn + j * 16 + fi][0];
        #pragma unroll
        for (int i = 0; i < 4; ++i)
            #pragma unroll
            for (int j = 0; j < 4; ++j)
                acc[i][j] = __builtin_amdgcn_mfma_f32_16x16x32_bf16(
                    af[i], bfr[j], acc[i][j], 0, 0, 0);
        __syncthreads();
    }

    #pragma unroll
    for (int i = 0; i < 4; ++i) {
        const int row0 = m0 + wm + i * 16 + quad * 4;
        #pragma unroll
        for (int r = 0; r < 4; ++r) {
            const float bv = BIAS ? bias[row0 + r] : 0.0f;
            #pragma unroll
            for (int j = 0; j < 4; ++j) {
                const int col = n0 + wn + j * 16 + fi;
                Cp[(size_t)(row0 + r) * ldC + col] = acc[i][j][r] + bv;
            }
        }
    }
}

// ---------------------------------------------------------------------------
// One wave per pixel, AH = (b, p, 384) f32: ch 0..63 = attn logits (n*16+q),
// ch 64..319 = hv (n*64+d).
// Phase A: lane = (n,q): gather 9 window logits (OOB logit = 0, matching the
//          reference's zero-padded unfold), softmax, store P[l][nq] to LDS.
// Phase B: lane = d: y[b,p,q*64+d] = head_b[d] + sum_{n,l} P[l][n16+q]*hv_l[n,d]
//          float2-paired accumulation (v_pk_fma-friendly), broadcast LDS reads.
// ---------------------------------------------------------------------------
__global__ __launch_bounds__(256) void attn_apply(
    const float* __restrict__ AH, const float* __restrict__ head_b,
    bf16* __restrict__ y)
{
    const int wv   = threadIdx.x >> 6;
    const int lane = threadIdx.x & 63;
    const int hw   = blockIdx.x * 4 + wv;
    const int b    = blockIdx.y;
    const int h    = hw >> 6, w = hw & 63;
    __shared__ float P[4][9][64];   // [wave][l][n*16+q]

    {
        float lg[9];
        #pragma unroll
        for (int i = 0; i < 3; ++i)
            #pragma unroll
            for (int j = 0; j < 3; ++j) {
                int hh = h + i - 1, ww = w + j - 1;
                bool ok = ((unsigned)hh < 64u) && ((unsigned)ww < 64u);
                lg[i * 3 + j] = ok ? AH[((size_t)b * HW_T + hh * 64 + ww) * 384 + lane]
                                   : 0.0f;
            }
        float m = lg[0];
        #pragma unroll
        for (int l = 1; l < 9; ++l) m = fmaxf(m, lg[l]);
        float e[9], s = 0.f;
        #pragma unroll
        for (int l = 0; l < 9; ++l) { e[l] = __expf(lg[l] - m); s += e[l]; }
        float inv = 1.0f / s;
        #pragma unroll
        for (int l = 0; l < 9; ++l) P[wv][l][lane] = e[l] * inv;
    }
    __syncthreads();

    float2 acc[8];
    {
        float hb = head_b[lane];
        #pragma unroll
        for (int qq = 0; qq < 8; ++qq) acc[qq] = make_float2(hb, hb);
    }

    #pragma unroll
    for (int i = 0; i < 3; ++i)
        #pragma unroll
        for (int j = 0; j < 3; ++j) {
            int hh = h + i - 1, ww = w + j - 1;
            if (((unsigned)hh < 64u) && ((unsigned)ww < 64u)) {  // wave-uniform
                const float* ap = AH + ((size_t)b * HW_T + hh * 64 + ww) * 384 + 64;
                #pragma unroll
                for (int n = 0; n < 4; ++n) {
                    const float hval = ap[n * 64 + lane];
                    const float2* pp = (const float2*)&P[wv][i * 3 + j][n * 16];
                    #pragma unroll
                    for (int qq = 0; qq < 8; ++qq) {
                        float2 pv = pp[qq];
                        acc[qq].x = fmaf(pv.x, hval, acc[qq].x);
                        acc[qq].y = fmaf(pv.y, hval, acc[qq].y);
                    }
                }
            }
        }

    // NOTE: acc[qq] covers q = n-interleaved? No: acc index qq pairs q=2qq,2qq+1
    // within each n-block of P; contributions from all n summed into same acc
    // because pp[qq] spans P[..][n*16 + 2qq .. 2qq+1] — q index is within-head
    // query id, identical across n. Store y[q*64+d].
    bf16* yp = y + ((size_t)b * HW_T + hw) * 1024 + lane;
    #pragma unroll
    for (int qq = 0; qq < 8; ++qq) {
        yp[(size_t)(2 * qq) * 64]     = __float2bfloat16(acc[qq].x);
        yp[(size_t)(2 * qq + 1) * 64] = __float2bfloat16(acc[qq].y);
    }
}

// ---------------------------------------------------------------------------
extern "C" void kernel_launch(void* const* d_in, const int* in_sizes, int n_in,
                              void* d_out, int out_size, void* d_ws, size_t ws_size,
                              hipStream_t stream) {
    (void)in_sizes; (void)n_in; (void)out_size; (void)ws_size;
    const float* x      = (const float*)d_in[0];   // (4,256,64,64)
    const float* kv_w   = (const float*)d_in[1];   // (512,256)
    const float* dot_w  = (const float*)d_in[2];   // (4,16,64)
    const float* head_w = (const float*)d_in[3];   // (64,256)
    const float* head_b = (const float*)d_in[4];   // (64,)
    const float* q_w    = (const float*)d_in[5];   // (256,1024)
    const float* q_b    = (const float*)d_in[6];   // (256,)
    float* z = (float*)d_out;                      // (4,256,64,64)

    // workspace (64.7 MB):
    //   xT   bf16 (B,4096,256)   8388608 B @ 0
    //   AH   f32  (B,4096,384)  25165824 B @ 8388608
    //   y    bf16 (B,4096,1024) 33554432 B @ 33554432
    //   W    bf16 (384,256)       196608 B @ 67108864
    //   qw_b bf16 (256,1024)      524288 B @ 67305472
    char* ws    = (char*)d_ws;
    bf16*  xT   = (bf16*) ws;
    float* AH   = (float*)(ws + 8388608);
    bf16*  y    = (bf16*) (ws + 33554432);
    bf16*  W    = (bf16*) (ws + 67108864);
    bf16*  qw_b = (bf16*) (ws + 67305472);

    // P0: fused weight build + q_w convert + x transpose
    fuse_w<<<dim3(384), 256, 0, stream>>>(kv_w, dot_w, head_w, W);
    convert_w<<<dim3(1024), 256, 0, stream>>>(q_w, qw_b, 256 * 1024);
    transpose_x<<<dim3(128, 8, B_T), 256, 0, stream>>>(x, xT);

    // K1: AH = xT @ W^T   (M=4096 per batch, N=384, K=256) -> pixel-major
    gemm_mfma_bt<false><<<dim3(3, 32, B_T), 256, 0, stream>>>(
        xT, W, nullptr, AH, 256, 384,
        (long)HW_T * 256, 0L, (long)HW_T * 384);

    // K4: windowed softmax + apply -> y (b, p, 1024) bf16
    attn_apply<<<dim3(1024, B_T), 256, 0, stream>>>(AH, head_b, y);

    // K5: z = q_w @ y + q_b  (M=256, N=4096 per batch, K=1024)
    gemm_mfma_bt<true><<<dim3(32, 2, B_T), 256, 0, stream>>>(
        qw_b, y, q_b, z, 1024, HW_T,
        0L, (long)HW_T * 1024, (long)256 * HW_T);
}

// Round 5
// 149.715 us; speedup vs baseline: 2.8056x; 1.0576x over previous
//
#include <hip/hip_runtime.h>
#include <hip/hip_bf16.h>
#include <cstdint>

typedef __hip_bfloat16 bf16;
using bf16x8 = __attribute__((ext_vector_type(8))) short;  // 8 bf16 (4 VGPRs)
using f32x4  = __attribute__((ext_vector_type(4))) float;

#define HW_T 4096   // H*W = 64*64
#define B_T  4

// async global->LDS, 16B per lane; LDS dest = wave-uniform base + lane*16
__device__ __forceinline__ void async_copy16(const bf16* g, bf16* l) {
    __builtin_amdgcn_global_load_lds(
        (const __attribute__((address_space(1))) void*)g,
        (__attribute__((address_space(3))) void*)l, 16, 0, 0);
}

// ---------------------------------------------------------------------------
// Prep: fused weights W (384 x 256) bf16 + q_w convert (256x1024 -> bf16).
//   W rows   0..63  : W[n*16+q, c] = sum_d dot_w[n,q,d] * kv_w[n*64+d, c]
//   W rows  64..319 : W[64+n*64+dh, c] = sum_dd head_w[dh, n*64+dd]*kv_w[256+n*64+dd, c]
//   W rows 320..383 : 0 (pad to N-tile)
// blocks 384..1407: qw_b convert
// ---------------------------------------------------------------------------
__global__ __launch_bounds__(256) void fuse_all(
    const float* __restrict__ kv_w, const float* __restrict__ dot_w,
    const float* __restrict__ head_w, const float* __restrict__ q_w,
    bf16* __restrict__ W, bf16* __restrict__ qw_b)
{
    const int rb = blockIdx.x;
    if (rb < 384) {
        const int r = rb, c = threadIdx.x;
        float acc = 0.f;
        if (r < 64) {
            const int n = r >> 4, q = r & 15;
            #pragma unroll 8
            for (int d = 0; d < 64; ++d)
                acc += dot_w[(n * 16 + q) * 64 + d] * kv_w[(size_t)(n * 64 + d) * 256 + c];
        } else if (r < 320) {
            const int rr = r - 64, n = rr >> 6, dh = rr & 63;
            #pragma unroll 8
            for (int dd = 0; dd < 64; ++dd)
                acc += head_w[dh * 256 + n * 64 + dd] * kv_w[(size_t)(256 + n * 64 + dd) * 256 + c];
        }
        W[r * 256 + c] = __float2bfloat16(acc);
    } else {
        const int i = (rb - 384) * 256 + threadIdx.x;   // 0 .. 262143
        qw_b[i] = __float2bfloat16(q_w[i]);
    }
}

// ---------------------------------------------------------------------------
// K1: AH (b, p, 384) f32 = x^T (pixels x 256, transposed on the fly from
// fp32 x (b, 256, 4096)) * W^T (384 x 256 bf16).
// 128x128 tile, BK=32, 512 threads (8 waves, 2x4), 4x2 16x16x32 MFMAs/wave.
// A staged manually (coalesced fp32 row loads -> cvt -> ds_write_b128 in
// fragment order, conflict-free); B staged via global_load_lds.
// ---------------------------------------------------------------------------
__global__ __launch_bounds__(512) void gemm_xw(
    const float* __restrict__ x, const bf16* __restrict__ W,
    float* __restrict__ AH)
{
    __shared__ __align__(16) bf16 As[4][128][8];  // [k>>3][m(pixel)][k&7]
    __shared__ __align__(16) bf16 Bs[4][128][8];  // [k>>3][n(chan)][k&7]
    const int tid  = threadIdx.x;
    const int wave = tid >> 6, lane = tid & 63;
    const int n0 = blockIdx.x * 128, m0 = blockIdx.y * 128, b = blockIdx.z;
    const float* xp0 = x + (size_t)b * 256 * HW_T;

    const int p  = tid & 127;   // A staging: pixel within tile
    const int c8 = tid >> 7;    // A staging: channel octet 0..3
    const int fi = lane & 15, quad = lane >> 4;
    const int wm = (wave >> 2) * 64, wn = (wave & 3) * 32;

    f32x4 acc[4][2] = {};

    for (int k0 = 0; k0 < 256; k0 += 32) {
        // B: W tile (128 rows x 32 k), one 16B async copy per thread
        async_copy16(W + (size_t)(n0 + (tid & 127)) * 256 + k0 + (tid >> 7) * 8,
                     &Bs[0][0][0] + (size_t)(wave * 64) * 8);
        // A: x tile (32 ch x 128 px) -> transpose+cvt -> fragment layout
        {
            const float* xp = xp0 + (size_t)(k0 + c8 * 8) * HW_T + m0 + p;
            bf16x8 pk;
            #pragma unroll
            for (int j = 0; j < 8; ++j) {
                bf16 h = __float2bfloat16(xp[(size_t)j * HW_T]);
                pk[j] = *reinterpret_cast<short*>(&h);
            }
            *(bf16x8*)&As[c8][p][0] = pk;
        }
        __syncthreads();
        bf16x8 af[4], bfr[2];
        #pragma unroll
        for (int i = 0; i < 4; ++i)
            af[i] = *(const bf16x8*)&As[quad][wm + i * 16 + fi][0];
        #pragma unroll
        for (int j = 0; j < 2; ++j)
            bfr[j] = *(const bf16x8*)&Bs[quad][wn + j * 16 + fi][0];
        #pragma unroll
        for (int i = 0; i < 4; ++i)
            #pragma unroll
            for (int j = 0; j < 2; ++j)
                acc[i][j] = __builtin_amdgcn_mfma_f32_16x16x32_bf16(
                    af[i], bfr[j], acc[i][j], 0, 0, 0);
        __syncthreads();
    }

    float* Cp = AH + (size_t)b * HW_T * 384;
    #pragma unroll
    for (int i = 0; i < 4; ++i) {
        const int row0 = m0 + wm + i * 16 + quad * 4;   // pixel
        #pragma unroll
        for (int r = 0; r < 4; ++r)
            #pragma unroll
            for (int j = 0; j < 2; ++j) {
                const int col = n0 + wn + j * 16 + fi;  // channel
                Cp[(size_t)(row0 + r) * 384 + col] = acc[i][j][r];
            }
    }
}

// ---------------------------------------------------------------------------
// K5: z (b, 256, 4096) f32 = qw_b (256 x 1024) * y (b, p, 1024)^T + q_b.
// Same 8-wave structure; both operands K-contiguous -> async staging.
// ---------------------------------------------------------------------------
__global__ __launch_bounds__(512) void gemm_qy(
    const bf16* __restrict__ Aw, const bf16* __restrict__ y,
    const float* __restrict__ q_b, float* __restrict__ z)
{
    __shared__ __align__(16) bf16 As[4][128][8];  // [k>>3][m(out ch)][k&7]
    __shared__ __align__(16) bf16 Bs[4][128][8];  // [k>>3][n(pixel)][k&7]
    const int tid  = threadIdx.x;
    const int wave = tid >> 6, lane = tid & 63;
    const int n0 = blockIdx.x * 128, m0 = blockIdx.y * 128, b = blockIdx.z;
    const bf16* Bp = y + (size_t)b * HW_T * 1024;

    const int sr = tid & 127, sq = tid >> 7;   // staging row / k-octet
    const int fi = lane & 15, quad = lane >> 4;
    const int wm = (wave >> 2) * 64, wn = (wave & 3) * 32;

    f32x4 acc[4][2] = {};

    for (int k0 = 0; k0 < 1024; k0 += 32) {
        async_copy16(Aw + (size_t)(m0 + sr) * 1024 + k0 + sq * 8,
                     &As[0][0][0] + (size_t)(wave * 64) * 8);
        async_copy16(Bp + (size_t)(n0 + sr) * 1024 + k0 + sq * 8,
                     &Bs[0][0][0] + (size_t)(wave * 64) * 8);
        __syncthreads();
        bf16x8 af[4], bfr[2];
        #pragma unroll
        for (int i = 0; i < 4; ++i)
            af[i] = *(const bf16x8*)&As[quad][wm + i * 16 + fi][0];
        #pragma unroll
        for (int j = 0; j < 2; ++j)
            bfr[j] = *(const bf16x8*)&Bs[quad][wn + j * 16 + fi][0];
        #pragma unroll
        for (int i = 0; i < 4; ++i)
            #pragma unroll
            for (int j = 0; j < 2; ++j)
                acc[i][j] = __builtin_amdgcn_mfma_f32_16x16x32_bf16(
                    af[i], bfr[j], acc[i][j], 0, 0, 0);
        __syncthreads();
    }

    float* Cp = z + (size_t)b * 256 * HW_T;
    #pragma unroll
    for (int i = 0; i < 4; ++i) {
        const int row0 = m0 + wm + i * 16 + quad * 4;   // out channel
        #pragma unroll
        for (int r = 0; r < 4; ++r) {
            const float bv = q_b[row0 + r];
            #pragma unroll
            for (int j = 0; j < 2; ++j) {
                const int col = n0 + wn + j * 16 + fi;  // pixel
                Cp[(size_t)(row0 + r) * HW_T + col] = acc[i][j][r] + bv;
            }
        }
    }
}

// ---------------------------------------------------------------------------
// One wave per pixel, AH = (b, p, 384) f32: ch 0..63 = attn logits (n*16+q),
// ch 64..319 = hv (n*64+d).
// Phase A: lane = (n,q): gather 9 window logits (OOB logit = 0, matching the
//          reference's zero-padded unfold), softmax, store P[l][nq] to LDS.
// Phase B: lane = d: y[b,p,q*64+d] = head_b[d] + sum_{n,l} P[l][n16+q]*hv_l[n,d]
// ---------------------------------------------------------------------------
__global__ __launch_bounds__(256) void attn_apply(
    const float* __restrict__ AH, const float* __restrict__ head_b,
    bf16* __restrict__ y)
{
    const int wv   = threadIdx.x >> 6;
    const int lane = threadIdx.x & 63;
    const int hw   = blockIdx.x * 4 + wv;
    const int b    = blockIdx.y;
    const int h    = hw >> 6, w = hw & 63;
    __shared__ float P[4][9][64];   // [wave][l][n*16+q]

    {
        float lg[9];
        #pragma unroll
        for (int i = 0; i < 3; ++i)
            #pragma unroll
            for (int j = 0; j < 3; ++j) {
                int hh = h + i - 1, ww = w + j - 1;
                bool ok = ((unsigned)hh < 64u) && ((unsigned)ww < 64u);
                lg[i * 3 + j] = ok ? AH[((size_t)b * HW_T + hh * 64 + ww) * 384 + lane]
                                   : 0.0f;
            }
        float m = lg[0];
        #pragma unroll
        for (int l = 1; l < 9; ++l) m = fmaxf(m, lg[l]);
        float e[9], s = 0.f;
        #pragma unroll
        for (int l = 0; l < 9; ++l) { e[l] = __expf(lg[l] - m); s += e[l]; }
        float inv = 1.0f / s;
        #pragma unroll
        for (int l = 0; l < 9; ++l) P[wv][l][lane] = e[l] * inv;
    }
    __syncthreads();

    float2 acc[8];
    {
        float hb = head_b[lane];
        #pragma unroll
        for (int qq = 0; qq < 8; ++qq) acc[qq] = make_float2(hb, hb);
    }

    #pragma unroll
    for (int i = 0; i < 3; ++i)
        #pragma unroll
        for (int j = 0; j < 3; ++j) {
            int hh = h + i - 1, ww = w + j - 1;
            if (((unsigned)hh < 64u) && ((unsigned)ww < 64u)) {  // wave-uniform
                const float* ap = AH + ((size_t)b * HW_T + hh * 64 + ww) * 384 + 64;
                #pragma unroll
                for (int n = 0; n < 4; ++n) {
                    const float hval = ap[n * 64 + lane];
                    const float2* pp = (const float2*)&P[wv][i * 3 + j][n * 16];
                    #pragma unroll
                    for (int qq = 0; qq < 8; ++qq) {
                        float2 pv = pp[qq];
                        acc[qq].x = fmaf(pv.x, hval, acc[qq].x);
                        acc[qq].y = fmaf(pv.y, hval, acc[qq].y);
                    }
                }
            }
        }

    bf16* yp = y + ((size_t)b * HW_T + hw) * 1024 + lane;
    #pragma unroll
    for (int qq = 0; qq < 8; ++qq) {
        yp[(size_t)(2 * qq) * 64]     = __float2bfloat16(acc[qq].x);
        yp[(size_t)(2 * qq + 1) * 64] = __float2bfloat16(acc[qq].y);
    }
}

// ---------------------------------------------------------------------------
extern "C" void kernel_launch(void* const* d_in, const int* in_sizes, int n_in,
                              void* d_out, int out_size, void* d_ws, size_t ws_size,
                              hipStream_t stream) {
    (void)in_sizes; (void)n_in; (void)out_size; (void)ws_size;
    const float* x      = (const float*)d_in[0];   // (4,256,64,64)
    const float* kv_w   = (const float*)d_in[1];   // (512,256)
    const float* dot_w  = (const float*)d_in[2];   // (4,16,64)
    const float* head_w = (const float*)d_in[3];   // (64,256)
    const float* head_b = (const float*)d_in[4];   // (64,)
    const float* q_w    = (const float*)d_in[5];   // (256,1024)
    const float* q_b    = (const float*)d_in[6];   // (256,)
    float* z = (float*)d_out;                      // (4,256,64,64)

    // workspace (59.4 MB):
    //   AH   f32  (B,4096,384)  25165824 B @ 0
    //   y    bf16 (B,4096,1024) 33554432 B @ 25165824
    //   W    bf16 (384,256)       196608 B @ 58720256
    //   qw_b bf16 (256,1024)      524288 B @ 58916864
    char* ws    = (char*)d_ws;
    float* AH   = (float*)ws;
    bf16*  y    = (bf16*) (ws + 25165824);
    bf16*  W    = (bf16*) (ws + 58720256);
    bf16*  qw_b = (bf16*) (ws + 58916864);

    // P0: fused weight build + q_w convert
    fuse_all<<<dim3(1408), 256, 0, stream>>>(kv_w, dot_w, head_w, q_w, W, qw_b);

    // K1: AH = x^T @ W^T  (M=4096/batch, N=384, K=256), transpose fused
    gemm_xw<<<dim3(3, 32, B_T), 512, 0, stream>>>(x, W, AH);

    // K4: windowed softmax + apply -> y (b, p, 1024) bf16
    attn_apply<<<dim3(1024, B_T), 256, 0, stream>>>(AH, head_b, y);

    // K5: z = qw_b @ y^T + q_b  (M=256, N=4096/batch, K=1024)
    gemm_qy<<<dim3(32, 2, B_T), 512, 0, stream>>>(qw_b, y, q_b, z);
}

// Round 6
// 138.447 us; speedup vs baseline: 3.0340x; 1.0814x over previous
//
#include <hip/hip_runtime.h>
#include <hip/hip_bf16.h>
#include <cstdint>

typedef __hip_bfloat16 bf16;
using bf16x8 = __attribute__((ext_vector_type(8))) short;  // 8 bf16 (4 VGPRs)
using f32x4  = __attribute__((ext_vector_type(4))) float;

#define HW_T 4096   // H*W = 64*64
#define B_T  4

// async global->LDS, 16B per lane; LDS dest = wave-uniform base + lane*16
__device__ __forceinline__ void async_copy16(const bf16* g, bf16* l) {
    __builtin_amdgcn_global_load_lds(
        (const __attribute__((address_space(1))) void*)g,
        (__attribute__((address_space(3))) void*)l, 16, 0, 0);
}
__device__ __forceinline__ short f2bs(float f) {
    bf16 h = __float2bfloat16(f);
    return *reinterpret_cast<short*>(&h);
}

// ---------------------------------------------------------------------------
// Prep: fused weights W (384 x 256) bf16 + q_w convert (256x1024 -> bf16).
//   W rows   0..63  : W[n*16+q, c] = sum_d dot_w[n,q,d] * kv_w[n*64+d, c]
//   W rows  64..319 : W[64+n*64+dh, c] = sum_dd head_w[dh, n*64+dd]*kv_w[256+n*64+dd, c]
//   W rows 320..383 : 0 (pad to N-tile)
// ---------------------------------------------------------------------------
__global__ __launch_bounds__(256) void fuse_all(
    const float* __restrict__ kv_w, const float* __restrict__ dot_w,
    const float* __restrict__ head_w, const float* __restrict__ q_w,
    bf16* __restrict__ W, bf16* __restrict__ qw_b)
{
    const int rb = blockIdx.x;
    if (rb < 384) {
        const int r = rb, c = threadIdx.x;
        float acc = 0.f;
        if (r < 64) {
            const int n = r >> 4, q = r & 15;
            #pragma unroll 8
            for (int d = 0; d < 64; ++d)
                acc += dot_w[(n * 16 + q) * 64 + d] * kv_w[(size_t)(n * 64 + d) * 256 + c];
        } else if (r < 320) {
            const int rr = r - 64, n = rr >> 6, dh = rr & 63;
            #pragma unroll 8
            for (int dd = 0; dd < 64; ++dd)
                acc += head_w[dh * 256 + n * 64 + dd] * kv_w[(size_t)(256 + n * 64 + dd) * 256 + c];
        }
        W[r * 256 + c] = __float2bfloat16(acc);
    } else {
        const int i = (rb - 384) * 256 + threadIdx.x;   // 0 .. 262143
        qw_b[i] = __float2bfloat16(q_w[i]);
    }
}

// ---------------------------------------------------------------------------
// K1: AH (b, p, 384) f32 = x^T (on-the-fly transpose of fp32 x) * W^T.
// Tile 64(px) x 128(ch), BK=32, 256 threads (4 waves), double-buffered LDS,
// stage-after-barrier prefetch. Grid 64 x 3 x 4 = 768 blocks (3 blocks/CU).
// ---------------------------------------------------------------------------
__global__ __launch_bounds__(256) void gemm_xw(
    const float* __restrict__ x, const bf16* __restrict__ W,
    float* __restrict__ AH)
{
    __shared__ __align__(16) bf16 As[2][4][64][8];   // [buf][k>>3][px][k&7]  2x4KB
    __shared__ __align__(16) bf16 Bs[2][4][128][8];  // [buf][k>>3][ch][k&7]  2x8KB
    const int tid  = threadIdx.x;
    const int wave = tid >> 6, lane = tid & 63;
    const int m0 = blockIdx.x * 64;     // pixel tile
    const int n0 = blockIdx.y * 128;    // channel tile
    const int b  = blockIdx.z;
    const float* xb = x + (size_t)b * 256 * HW_T;

    const int px = tid & 63, c8 = tid >> 6;  // A staging role
    const int fi = lane & 15, quad = lane >> 4;
    const int wn = wave * 32;

    f32x4 acc[4][2] = {};
    float xr[8];

    // prologue: stage iter 0 into buf 0
    {
        const float* xp = xb + (size_t)(c8 * 8) * HW_T + m0 + px;
        #pragma unroll
        for (int j = 0; j < 8; ++j) xr[j] = xp[(size_t)j * HW_T];
        #pragma unroll
        for (int i = 0; i < 2; ++i) {
            const int slot = i * 256 + tid;
            const int r = slot & 127, q = slot >> 7;
            async_copy16(W + (size_t)(n0 + r) * 256 + q * 8,
                         &Bs[0][0][0][0] + (size_t)(i * 256 + wave * 64) * 8);
        }
        bf16x8 pk;
        #pragma unroll
        for (int j = 0; j < 8; ++j) pk[j] = f2bs(xr[j]);
        *(bf16x8*)&As[0][c8][px][0] = pk;
    }

    for (int it = 0; it < 8; ++it) {
        const int cur = it & 1;
        __syncthreads();                       // buf[cur] ready
        if (it < 7) {                          // prefetch buf[cur^1] (flies during MFMA)
            const int k1 = (it + 1) * 32;
            const float* xp = xb + (size_t)(k1 + c8 * 8) * HW_T + m0 + px;
            #pragma unroll
            for (int j = 0; j < 8; ++j) xr[j] = xp[(size_t)j * HW_T];
            #pragma unroll
            for (int i = 0; i < 2; ++i) {
                const int slot = i * 256 + tid;
                const int r = slot & 127, q = slot >> 7;
                async_copy16(W + (size_t)(n0 + r) * 256 + k1 + q * 8,
                             &Bs[cur ^ 1][0][0][0] + (size_t)(i * 256 + wave * 64) * 8);
            }
        }
        bf16x8 af[4], bfr[2];
        #pragma unroll
        for (int i = 0; i < 4; ++i)
            af[i] = *(const bf16x8*)&As[cur][quad][i * 16 + fi][0];
        #pragma unroll
        for (int j = 0; j < 2; ++j)
            bfr[j] = *(const bf16x8*)&Bs[cur][quad][wn + j * 16 + fi][0];
        #pragma unroll
        for (int i = 0; i < 4; ++i)
            #pragma unroll
            for (int j = 0; j < 2; ++j)
                acc[i][j] = __builtin_amdgcn_mfma_f32_16x16x32_bf16(
                    af[i], bfr[j], acc[i][j], 0, 0, 0);
        if (it < 7) {                          // write A prefetch after MFMA issue
            bf16x8 pk;
            #pragma unroll
            for (int j = 0; j < 8; ++j) pk[j] = f2bs(xr[j]);
            *(bf16x8*)&As[cur ^ 1][c8][px][0] = pk;
        }
    }

    float* Cp = AH + (size_t)b * HW_T * 384;
    #pragma unroll
    for (int i = 0; i < 4; ++i) {
        const int p = m0 + i * 16 + quad * 4;
        #pragma unroll
        for (int r = 0; r < 4; ++r)
            #pragma unroll
            for (int j = 0; j < 2; ++j)
                Cp[(size_t)(p + r) * 384 + n0 + wn + j * 16 + fi] = acc[i][j][r];
    }
}

// ---------------------------------------------------------------------------
// K5: z (b, 256, 4096) f32 = qw_b (256x1024) @ y (b, p, 1024)^T + q_b.
// Tile 64(out-ch) x 128(px), BK=32, 4 waves, double-buffered, grid 4 x 32 x 4
// = 512 blocks (2 blocks/CU; x-dim = m so same-pixel-slice blocks are adjacent).
// ---------------------------------------------------------------------------
__global__ __launch_bounds__(256) void gemm_qy(
    const bf16* __restrict__ Aw, const bf16* __restrict__ y,
    const float* __restrict__ q_b, float* __restrict__ z)
{
    __shared__ __align__(16) bf16 As[2][4][64][8];
    __shared__ __align__(16) bf16 Bs[2][4][128][8];
    const int tid  = threadIdx.x;
    const int wave = tid >> 6, lane = tid & 63;
    const int m0 = blockIdx.x * 64;     // out-channel tile
    const int n0 = blockIdx.y * 128;    // pixel tile
    const int b  = blockIdx.z;
    const bf16* Bp = y + (size_t)b * HW_T * 1024;

    const int fi = lane & 15, quad = lane >> 4;
    const int wn = wave * 32;

    f32x4 acc[4][2] = {};

    {   // stage iter 0
        async_copy16(Aw + (size_t)(m0 + lane) * 1024 + wave * 8,
                     &As[0][0][0][0] + (size_t)tid * 8);
        #pragma unroll
        for (int i = 0; i < 2; ++i) {
            const int slot = i * 256 + tid;
            const int r = slot & 127, q = slot >> 7;
            async_copy16(Bp + (size_t)(n0 + r) * 1024 + q * 8,
                         &Bs[0][0][0][0] + (size_t)(i * 256 + wave * 64) * 8);
        }
    }
    for (int it = 0; it < 32; ++it) {
        const int cur = it & 1;
        __syncthreads();
        if (it < 31) {
            const int k1 = (it + 1) * 32;
            async_copy16(Aw + (size_t)(m0 + lane) * 1024 + k1 + wave * 8,
                         &As[cur ^ 1][0][0][0] + (size_t)tid * 8);
            #pragma unroll
            for (int i = 0; i < 2; ++i) {
                const int slot = i * 256 + tid;
                const int r = slot & 127, q = slot >> 7;
                async_copy16(Bp + (size_t)(n0 + r) * 1024 + k1 + q * 8,
                             &Bs[cur ^ 1][0][0][0] + (size_t)(i * 256 + wave * 64) * 8);
            }
        }
        bf16x8 af[4], bfr[2];
        #pragma unroll
        for (int i = 0; i < 4; ++i)
            af[i] = *(const bf16x8*)&As[cur][quad][i * 16 + fi][0];
        #pragma unroll
        for (int j = 0; j < 2; ++j)
            bfr[j] = *(const bf16x8*)&Bs[cur][quad][wn + j * 16 + fi][0];
        #pragma unroll
        for (int i = 0; i < 4; ++i)
            #pragma unroll
            for (int j = 0; j < 2; ++j)
                acc[i][j] = __builtin_amdgcn_mfma_f32_16x16x32_bf16(
                    af[i], bfr[j], acc[i][j], 0, 0, 0);
    }

    float* Cp = z + (size_t)b * 256 * HW_T;
    #pragma unroll
    for (int i = 0; i < 4; ++i) {
        const int row0 = m0 + i * 16 + quad * 4;
        #pragma unroll
        for (int r = 0; r < 4; ++r) {
            const float bv = q_b[row0 + r];
            #pragma unroll
            for (int j = 0; j < 2; ++j)
                Cp[(size_t)(row0 + r) * HW_T + n0 + wn + j * 16 + fi] = acc[i][j][r] + bv;
        }
    }
}

// ---------------------------------------------------------------------------
// One wave per pixel. AH = (b,p,384) f32: ch 0..63 = logits (n*16+q),
// ch 64..319 = hv (n*64+d).
// Phase A (lane = n*16+q): branch-free clamped loads, softmax over 9 windows
// with OOB logit = 0 (reference zero-pads), then P *= ok (OOB v is 0).
// Phase B: y(16q x 64d) = P(16 x 36) @ HV(36 x 64) as 4 MFMA 16x16x32
// (k = l*4+n, l<8) + fp32 tail for l=8. C layout: row=q, col=d-sub.
// ---------------------------------------------------------------------------
__global__ __launch_bounds__(256) void attn_apply(
    const float* __restrict__ AH, const float* __restrict__ head_b,
    bf16* __restrict__ y)
{
    const int wv   = threadIdx.x >> 6;
    const int lane = threadIdx.x & 63;
    const int hw   = blockIdx.x * 4 + wv;
    const int b    = blockIdx.y;
    const int h    = hw >> 6, w = hw & 63;
    __shared__ float P[4][9][64];   // [wave][l][n*16+q]

    int   off[9];
    float okf[9];
    #pragma unroll
    for (int l = 0; l < 9; ++l) {
        const int i = l / 3, j = l % 3;
        const int hh = h + i - 1, ww = w + j - 1;
        const bool ok = ((unsigned)hh < 64u) && ((unsigned)ww < 64u);
        off[l] = ((b * HW_T) + (ok ? hh : h) * 64 + (ok ? ww : w)) * 384;
        okf[l] = ok ? 1.0f : 0.0f;
    }

    {   // phase A
        float lg[9];
        #pragma unroll
        for (int l = 0; l < 9; ++l) lg[l] = AH[(size_t)off[l] + lane] * okf[l];
        float m = lg[0];
        #pragma unroll
        for (int l = 1; l < 9; ++l) m = fmaxf(m, lg[l]);
        float e[9], s = 0.f;
        #pragma unroll
        for (int l = 0; l < 9; ++l) { e[l] = __expf(lg[l] - m); s += e[l]; }
        const float inv = 1.0f / s;
        #pragma unroll
        for (int l = 0; l < 9; ++l) P[wv][l][lane] = e[l] * inv * okf[l];
    }
    __syncthreads();

    const int fi = lane & 15, quad = lane >> 4;

    // A-fragment: P[q=fi][k=quad*8+j], k = l*4+n (l<8)
    bf16x8 afr;
    #pragma unroll
    for (int j = 0; j < 8; ++j) {
        const int k = quad * 8 + j;
        afr[j] = f2bs(P[wv][k >> 2][(k & 3) * 16 + fi]);
    }

    f32x4 acc[4];
    #pragma unroll
    for (int dt = 0; dt < 4; ++dt) {
        const float hb = head_b[dt * 16 + fi];
        acc[dt][0] = hb; acc[dt][1] = hb; acc[dt][2] = hb; acc[dt][3] = hb;
    }

    #pragma unroll
    for (int dt = 0; dt < 4; ++dt) {
        bf16x8 bfr;   // B-fragment: HV[k=quad*8+j][d=dt*16+fi]
        #pragma unroll
        for (int j = 0; j < 8; ++j) {
            const int k = quad * 8 + j;
            const int l = k >> 2, n = k & 3;
            bfr[j] = f2bs(AH[(size_t)off[l] + 64 + n * 64 + dt * 16 + fi]);
        }
        acc[dt] = __builtin_amdgcn_mfma_f32_16x16x32_bf16(afr, bfr, acc[dt], 0, 0, 0);
    }

    // tail: l = 8, fp32
    #pragma unroll
    for (int n = 0; n < 4; ++n) {
        float pv[4];
        #pragma unroll
        for (int r = 0; r < 4; ++r) pv[r] = P[wv][8][n * 16 + quad * 4 + r];
        #pragma unroll
        for (int dt = 0; dt < 4; ++dt) {
            const float hval = AH[(size_t)off[8] + 64 + n * 64 + dt * 16 + fi];
            #pragma unroll
            for (int r = 0; r < 4; ++r) acc[dt][r] = fmaf(pv[r], hval, acc[dt][r]);
        }
    }

    bf16* yp = y + ((size_t)b * HW_T + hw) * 1024;
    #pragma unroll
    for (int dt = 0; dt < 4; ++dt)
        #pragma unroll
        for (int r = 0; r < 4; ++r)
            yp[(size_t)(quad * 4 + r) * 64 + dt * 16 + fi] = __float2bfloat16(acc[dt][r]);
}

// ---------------------------------------------------------------------------
extern "C" void kernel_launch(void* const* d_in, const int* in_sizes, int n_in,
                              void* d_out, int out_size, void* d_ws, size_t ws_size,
                              hipStream_t stream) {
    (void)in_sizes; (void)n_in; (void)out_size; (void)ws_size;
    const float* x      = (const float*)d_in[0];   // (4,256,64,64)
    const float* kv_w   = (const float*)d_in[1];   // (512,256)
    const float* dot_w  = (const float*)d_in[2];   // (4,16,64)
    const float* head_w = (const float*)d_in[3];   // (64,256)
    const float* head_b = (const float*)d_in[4];   // (64,)
    const float* q_w    = (const float*)d_in[5];   // (256,1024)
    const float* q_b    = (const float*)d_in[6];   // (256,)
    float* z = (float*)d_out;                      // (4,256,64,64)

    // workspace (59.4 MB):
    //   AH   f32  (B,4096,384)  25165824 B @ 0
    //   y    bf16 (B,4096,1024) 33554432 B @ 25165824
    //   W    bf16 (384,256)       196608 B @ 58720256
    //   qw_b bf16 (256,1024)      524288 B @ 58916864
    char* ws    = (char*)d_ws;
    float* AH   = (float*)ws;
    bf16*  y    = (bf16*) (ws + 25165824);
    bf16*  W    = (bf16*) (ws + 58720256);
    bf16*  qw_b = (bf16*) (ws + 58916864);

    fuse_all<<<dim3(1408), 256, 0, stream>>>(kv_w, dot_w, head_w, q_w, W, qw_b);

    // K1: AH = x^T @ W^T  (M=4096/batch, N=384, K=256), transpose fused
    gemm_xw<<<dim3(64, 3, B_T), 256, 0, stream>>>(x, W, AH);

    // K4: windowed softmax + apply -> y (b, p, 1024) bf16
    attn_apply<<<dim3(1024, B_T), 256, 0, stream>>>(AH, head_b, y);

    // K5: z = qw_b @ y^T + q_b  (M=256, N=4096/batch, K=1024)
    gemm_qy<<<dim3(4, 32, B_T), 256, 0, stream>>>(qw_b, y, q_b, z);
}

// Round 7
// 128.433 us; speedup vs baseline: 3.2705x; 1.0780x over previous
//
#include <hip/hip_runtime.h>
#include <hip/hip_bf16.h>
#include <cstdint>

typedef __hip_bfloat16 bf16;
using bf16x8 = __attribute__((ext_vector_type(8))) short;  // 8 bf16 (4 VGPRs)
using f32x4  = __attribute__((ext_vector_type(4))) float;

#define HW_T 4096   // H*W = 64*64
#define B_T  4

// async global->LDS, 16B per lane; LDS dest = wave-uniform base + lane*16
__device__ __forceinline__ void async_copy16(const bf16* g, bf16* l) {
    __builtin_amdgcn_global_load_lds(
        (const __attribute__((address_space(1))) void*)g,
        (__attribute__((address_space(3))) void*)l, 16, 0, 0);
}
__device__ __forceinline__ short f2bs(float f) {
    bf16 h = __float2bfloat16(f);
    return *reinterpret_cast<short*>(&h);
}
__device__ __forceinline__ float bs2f(short s) {
    unsigned int u = ((unsigned int)(unsigned short)s) << 16;
    float f;
    __builtin_memcpy(&f, &u, 4);
    return f;
}

// ---------------------------------------------------------------------------
// Prep: fused weights W (384 x 256) bf16 + q_w convert (256x1024 -> bf16).
//   W rows   0..63  : W[n*16+q, c] = sum_d dot_w[n,q,d] * kv_w[n*64+d, c]
//   W rows  64..319 : W[64+n*64+dh, c] = sum_dd head_w[dh, n*64+dd]*kv_w[256+n*64+dd, c]
//   W rows 320..383 : 0 (pad to N-tile)
// ---------------------------------------------------------------------------
__global__ __launch_bounds__(256) void fuse_all(
    const float* __restrict__ kv_w, const float* __restrict__ dot_w,
    const float* __restrict__ head_w, const float* __restrict__ q_w,
    bf16* __restrict__ W, bf16* __restrict__ qw_b)
{
    const int rb = blockIdx.x;
    if (rb < 384) {
        const int r = rb, c = threadIdx.x;
        float acc = 0.f;
        if (r < 64) {
            const int n = r >> 4, q = r & 15;
            #pragma unroll 8
            for (int d = 0; d < 64; ++d)
                acc += dot_w[(n * 16 + q) * 64 + d] * kv_w[(size_t)(n * 64 + d) * 256 + c];
        } else if (r < 320) {
            const int rr = r - 64, n = rr >> 6, dh = rr & 63;
            #pragma unroll 8
            for (int dd = 0; dd < 64; ++dd)
                acc += head_w[dh * 256 + n * 64 + dd] * kv_w[(size_t)(256 + n * 64 + dd) * 256 + c];
        }
        W[r * 256 + c] = __float2bfloat16(acc);
    } else {
        const int i = (rb - 384) * 256 + threadIdx.x;   // 0 .. 262143
        qw_b[i] = __float2bfloat16(q_w[i]);
    }
}

// ---------------------------------------------------------------------------
// K1: AH (b, p, 384) bf16 = x^T (on-the-fly transpose of fp32 x) * W^T.
// Tile 64(px) x 128(ch), BK=32, 256 threads (4 waves), double-buffered LDS.
// ---------------------------------------------------------------------------
__global__ __launch_bounds__(256) void gemm_xw(
    const float* __restrict__ x, const bf16* __restrict__ W,
    bf16* __restrict__ AH)
{
    __shared__ __align__(16) bf16 As[2][4][64][8];   // [buf][k>>3][px][k&7]
    __shared__ __align__(16) bf16 Bs[2][4][128][8];  // [buf][k>>3][ch][k&7]
    const int tid  = threadIdx.x;
    const int wave = tid >> 6, lane = tid & 63;
    const int m0 = blockIdx.x * 64;     // pixel tile
    const int n0 = blockIdx.y * 128;    // channel tile
    const int b  = blockIdx.z;
    const float* xb = x + (size_t)b * 256 * HW_T;

    const int px = tid & 63, c8 = tid >> 6;  // A staging role
    const int fi = lane & 15, quad = lane >> 4;
    const int wn = wave * 32;

    f32x4 acc[4][2] = {};
    float xr[8];

    {   // prologue: stage iter 0 into buf 0
        const float* xp = xb + (size_t)(c8 * 8) * HW_T + m0 + px;
        #pragma unroll
        for (int j = 0; j < 8; ++j) xr[j] = xp[(size_t)j * HW_T];
        #pragma unroll
        for (int i = 0; i < 2; ++i) {
            const int slot = i * 256 + tid;
            const int r = slot & 127, q = slot >> 7;
            async_copy16(W + (size_t)(n0 + r) * 256 + q * 8,
                         &Bs[0][0][0][0] + (size_t)(i * 256 + wave * 64) * 8);
        }
        bf16x8 pk;
        #pragma unroll
        for (int j = 0; j < 8; ++j) pk[j] = f2bs(xr[j]);
        *(bf16x8*)&As[0][c8][px][0] = pk;
    }

    for (int it = 0; it < 8; ++it) {
        const int cur = it & 1;
        __syncthreads();                       // buf[cur] ready
        if (it < 7) {
            const int k1 = (it + 1) * 32;
            const float* xp = xb + (size_t)(k1 + c8 * 8) * HW_T + m0 + px;
            #pragma unroll
            for (int j = 0; j < 8; ++j) xr[j] = xp[(size_t)j * HW_T];
            #pragma unroll
            for (int i = 0; i < 2; ++i) {
                const int slot = i * 256 + tid;
                const int r = slot & 127, q = slot >> 7;
                async_copy16(W + (size_t)(n0 + r) * 256 + k1 + q * 8,
                             &Bs[cur ^ 1][0][0][0] + (size_t)(i * 256 + wave * 64) * 8);
            }
        }
        bf16x8 af[4], bfr[2];
        #pragma unroll
        for (int i = 0; i < 4; ++i)
            af[i] = *(const bf16x8*)&As[cur][quad][i * 16 + fi][0];
        #pragma unroll
        for (int j = 0; j < 2; ++j)
            bfr[j] = *(const bf16x8*)&Bs[cur][quad][wn + j * 16 + fi][0];
        #pragma unroll
        for (int i = 0; i < 4; ++i)
            #pragma unroll
            for (int j = 0; j < 2; ++j)
                acc[i][j] = __builtin_amdgcn_mfma_f32_16x16x32_bf16(
                    af[i], bfr[j], acc[i][j], 0, 0, 0);
        if (it < 7) {
            bf16x8 pk;
            #pragma unroll
            for (int j = 0; j < 8; ++j) pk[j] = f2bs(xr[j]);
            *(bf16x8*)&As[cur ^ 1][c8][px][0] = pk;
        }
    }

    bf16* Cp = AH + (size_t)b * HW_T * 384;
    #pragma unroll
    for (int i = 0; i < 4; ++i) {
        const int p = m0 + i * 16 + quad * 4;
        #pragma unroll
        for (int r = 0; r < 4; ++r)
            #pragma unroll
            for (int j = 0; j < 2; ++j)
                Cp[(size_t)(p + r) * 384 + n0 + wn + j * 16 + fi] =
                    __float2bfloat16(acc[i][j][r]);
    }
}

// ---------------------------------------------------------------------------
// Fused K4+K5: block = one image row (64 px), 512 threads (8 waves).
// AH (b,p,384) bf16: ch 0..63 = logits (n*16+q), ch 64..319 = hv (n*64+d).
// Phase 1 (8 px/wave): softmax over 9 zero-padded window logits; P -> per-wave
//   LDS scratch; y(16q x 64d) = P(16x36) @ HV(36x64) as 4 MFMAs + fp32 tail;
//   y -> LDS tile [64 px][1032] bf16 (pad 8 -> conflict-free b128 reads).
// Phase 2: z tile (256 ch x 64 px, K=1024): wave w owns ch 32w..32w+31.
//   A-fragments from qw (global/L2, 1-iter register prefetch), B-fragments
//   ds_read_b128 from y LDS. NO barriers in the K-loop.
// ---------------------------------------------------------------------------
#define YPAD 1032
#define ATTN_LDS (64 * YPAD * 2 + 8 * 9 * 64 * 4)   // 132096 + 18432 = 150528

__global__ __launch_bounds__(512) void attn_qy(
    const bf16* __restrict__ AH, const float* __restrict__ head_b,
    const bf16* __restrict__ qw, const float* __restrict__ q_b,
    float* __restrict__ z)
{
    extern __shared__ __align__(16) char smem[];
    bf16*  yL = (bf16*)smem;                             // [64][YPAD]
    float* Pm = (float*)(smem + 64 * YPAD * 2) + (threadIdx.x >> 6) * 9 * 64;

    const int tid  = threadIdx.x;
    const int wave = tid >> 6, lane = tid & 63;
    const int p0  = blockIdx.x * 64;        // global pixel base (row-aligned)
    const int b   = p0 >> 12;
    const int hw0 = p0 & 4095;
    const int h   = hw0 >> 6;
    const int fi = lane & 15, quad = lane >> 4;
    const ushort* AHu = (const ushort*)AH;

    float hb[4];
    #pragma unroll
    for (int dt = 0; dt < 4; ++dt) hb[dt] = head_b[dt * 16 + fi];

    // ---------------- phase 1 ----------------
    for (int pi = 0; pi < 8; ++pi) {
        const int w = wave * 8 + pi;
        int off[9]; float okf[9];
        #pragma unroll
        for (int l = 0; l < 9; ++l) {
            const int i = l / 3, j = l % 3;
            const int hh = h + i - 1, ww = w + j - 1;
            const bool ok = ((unsigned)hh < 64u) && ((unsigned)ww < 64u);
            off[l] = ((b << 12) + (ok ? hh : h) * 64 + (ok ? ww : w)) * 384;
            okf[l] = ok ? 1.0f : 0.0f;
        }
        {   // softmax over zero-padded logits (lane = n*16+q)
            float lg[9];
            #pragma unroll
            for (int l = 0; l < 9; ++l)
                lg[l] = bs2f((short)AHu[(size_t)off[l] + lane]) * okf[l];
            float m = lg[0];
            #pragma unroll
            for (int l = 1; l < 9; ++l) m = fmaxf(m, lg[l]);
            float e[9], s = 0.f;
            #pragma unroll
            for (int l = 0; l < 9; ++l) { e[l] = __expf(lg[l] - m); s += e[l]; }
            const float inv = 1.0f / s;
            #pragma unroll
            for (int l = 0; l < 9; ++l) Pm[l * 64 + lane] = e[l] * inv * okf[l];
        }
        __syncthreads();   // P visible wave-wide (uniform barrier)

        // A-fragment: P[q=fi][k=quad*8+j], k=(l,n): l=k>>2, n=k&3 (l<8)
        bf16x8 afr;
        #pragma unroll
        for (int j = 0; j < 8; ++j) {
            const int k = quad * 8 + j;
            afr[j] = f2bs(Pm[(k >> 2) * 64 + (k & 3) * 16 + fi]);
        }
        f32x4 acc[4];
        #pragma unroll
        for (int dt = 0; dt < 4; ++dt) {
            acc[dt][0] = hb[dt]; acc[dt][1] = hb[dt];
            acc[dt][2] = hb[dt]; acc[dt][3] = hb[dt];
        }
        #pragma unroll
        for (int dt = 0; dt < 4; ++dt) {
            bf16x8 bfr;   // HV[k][d=dt*16+fi], already bf16 in AH
            #pragma unroll
            for (int j = 0; j < 8; ++j) {
                const int k = quad * 8 + j;
                bfr[j] = (short)AHu[(size_t)off[k >> 2] + 64 + (k & 3) * 64 + dt * 16 + fi];
            }
            acc[dt] = __builtin_amdgcn_mfma_f32_16x16x32_bf16(afr, bfr, acc[dt], 0, 0, 0);
        }
        // tail: l = 8, fp32
        #pragma unroll
        for (int n = 0; n < 4; ++n) {
            float pv[4];
            #pragma unroll
            for (int r = 0; r < 4; ++r) pv[r] = Pm[8 * 64 + n * 16 + quad * 4 + r];
            #pragma unroll
            for (int dt = 0; dt < 4; ++dt) {
                const float hval =
                    bs2f((short)AHu[(size_t)off[8] + 64 + n * 64 + dt * 16 + fi]);
                #pragma unroll
                for (int r = 0; r < 4; ++r) acc[dt][r] = fmaf(pv[r], hval, acc[dt][r]);
            }
        }
        // y -> LDS: yL[w][(quad*4+r)*64 + dt*16+fi]
        #pragma unroll
        for (int dt = 0; dt < 4; ++dt)
            #pragma unroll
            for (int r = 0; r < 4; ++r)
                yL[(size_t)w * YPAD + (quad * 4 + r) * 64 + dt * 16 + fi] =
                    __float2bfloat16(acc[dt][r]);
    }
    __syncthreads();   // y tile complete

    // ---------------- phase 2: z = qw @ y^T + q_b ----------------
    f32x4 zacc[2][4] = {};
    bf16x8 af[2], afn[2];
    #pragma unroll
    for (int i = 0; i < 2; ++i)
        af[i] = *(const bf16x8*)&qw[(size_t)(wave * 32 + i * 16 + fi) * 1024 + quad * 8];

    #pragma unroll 2
    for (int k0 = 0; k0 < 1024; k0 += 32) {
        if (k0 < 992) {
            #pragma unroll
            for (int i = 0; i < 2; ++i)
                afn[i] = *(const bf16x8*)&qw[(size_t)(wave * 32 + i * 16 + fi) * 1024
                                             + k0 + 32 + quad * 8];
        }
        bf16x8 bfr[4];
        #pragma unroll
        for (int j = 0; j < 4; ++j)
            bfr[j] = *(const bf16x8*)&yL[(size_t)(j * 16 + fi) * YPAD + k0 + quad * 8];
        #pragma unroll
        for (int i = 0; i < 2; ++i)
            #pragma unroll
            for (int j = 0; j < 4; ++j)
                zacc[i][j] = __builtin_amdgcn_mfma_f32_16x16x32_bf16(
                    af[i], bfr[j], zacc[i][j], 0, 0, 0);
        af[0] = afn[0]; af[1] = afn[1];
    }

    #pragma unroll
    for (int i = 0; i < 2; ++i) {
        const int row0 = wave * 32 + i * 16 + quad * 4;
        #pragma unroll
        for (int r = 0; r < 4; ++r) {
            const float bv = q_b[row0 + r];
            #pragma unroll
            for (int j = 0; j < 4; ++j)
                z[((size_t)(b * 256 + row0 + r)) * HW_T + hw0 + j * 16 + fi] =
                    zacc[i][j][r] + bv;
        }
    }
}

// ---------------------------------------------------------------------------
extern "C" void kernel_launch(void* const* d_in, const int* in_sizes, int n_in,
                              void* d_out, int out_size, void* d_ws, size_t ws_size,
                              hipStream_t stream) {
    (void)in_sizes; (void)n_in; (void)out_size; (void)ws_size;
    const float* x      = (const float*)d_in[0];   // (4,256,64,64)
    const float* kv_w   = (const float*)d_in[1];   // (512,256)
    const float* dot_w  = (const float*)d_in[2];   // (4,16,64)
    const float* head_w = (const float*)d_in[3];   // (64,256)
    const float* head_b = (const float*)d_in[4];   // (64,)
    const float* q_w    = (const float*)d_in[5];   // (256,1024)
    const float* q_b    = (const float*)d_in[6];   // (256,)
    float* z = (float*)d_out;                      // (4,256,64,64)

    // workspace (13.3 MB):
    //   AH   bf16 (B,4096,384) 12582912 B @ 0
    //   W    bf16 (384,256)      196608 B @ 12582912
    //   qw_b bf16 (256,1024)     524288 B @ 12779520
    char* ws    = (char*)d_ws;
    bf16*  AH   = (bf16*)ws;
    bf16*  W    = (bf16*)(ws + 12582912);
    bf16*  qw_b = (bf16*)(ws + 12779520);

    // opt-in to >64KB dynamic LDS for the fused kernel (idempotent, host-side)
    static bool attr_done = []() {
        hipFuncSetAttribute((const void*)attn_qy,
                            hipFuncAttributeMaxDynamicSharedMemorySize, ATTN_LDS);
        return true;
    }();
    (void)attr_done;

    fuse_all<<<dim3(1408), 256, 0, stream>>>(kv_w, dot_w, head_w, q_w, W, qw_b);

    // K1: AH = x^T @ W^T  (M=4096/batch, N=384, K=256), transpose fused, bf16 out
    gemm_xw<<<dim3(64, 3, B_T), 256, 0, stream>>>(x, W, AH);

    // K4+K5 fused: softmax/apply + z = qw @ y^T + q_b (y never leaves LDS)
    attn_qy<<<dim3(256), 512, ATTN_LDS, stream>>>(AH, head_b, qw_b, q_b, z);
}